// Round 5
// baseline (1170.696 us; speedup 1.0000x reference)
//
#include <hip/hip_runtime.h>
#include <hip/hip_bf16.h>
#include <math.h>

// Problem sizes (fixed): B=4, M=4096, D=1024, H=16, d=64, R=64
#define BM 16384
#define INV_SQRT_RH 0.17677669529663687f

typedef _Float16 half8 __attribute__((ext_vector_type(8)));
typedef _Float16 half4v __attribute__((ext_vector_type(4)));
typedef float f32x4 __attribute__((ext_vector_type(4)));

#define GLD16(gp, lp) __builtin_amdgcn_global_load_lds((const __attribute__((address_space(1))) void*)(gp), (__attribute__((address_space(3))) void*)(lp), 16, 0, 0)

// ---------------------------------------------------------------------------
// DFT matrices.
// C_[n][j]: fx = x @ C_  (n = time index, j = freq-concat index)
// Gt[n][col] = G[col][n]: y = out2 @ G, stored transposed (B-operand layout)
// ---------------------------------------------------------------------------
__global__ __launch_bounds__(256) void build_CG(float* __restrict__ Cm, float* __restrict__ Gt) {
    int idx = blockIdx.x * 256 + threadIdx.x;
    const float w = 6.28318530717958647692f / 1024.0f;
    if (idx < 1048576) {
        int n = idx >> 10, j = idx & 1023;
        float val;
        if (j <= 512) {
            int red = (n * j) & 1023;
            val = cosf(red * w) * (1.0f / 1024.0f);
        } else {
            int tt = j - 513;
            int red = (n * tt) & 1023;
            val = sinf(red * w) * (1.0f / 1024.0f);
        }
        Cm[idx] = val;
    } else if (idx < 2097152) {
        int l = idx - 1048576;
        int n = l >> 10, col = l & 1023;
        float val;
        if (col < 512) {
            int red = (n * col) & 1023;
            val = (col == 0 ? 1.0f : 2.0f) * cosf(red * w);
        } else {
            int tt = col - 512;
            int red = (n * tt) & 1023;
            val = (tt == 0) ? 0.0f : 2.0f * sinf(red * w);
        }
        Gt[l] = val;
    }
}

__global__ __launch_bounds__(256) void zero_kernel(float* __restrict__ p, int n) {
    int i = blockIdx.x * 256 + threadIdx.x;
    if (i < n) p[i] = 0.0f;
}

// bG[n] = sum_col bp[col]*Gt[n][col]
__global__ __launch_bounds__(256) void build_bG(const float* __restrict__ bp,
                                                const float* __restrict__ Gt,
                                                float* __restrict__ bG) {
    int n = blockIdx.x, t = threadIdx.x;
    float s = 0.0f;
    for (int j = t; j < 1024; j += 256) s += bp[j] * Gt[(size_t)n * 1024 + j];
    __shared__ float red[256];
    red[t] = s;
    __syncthreads();
    for (int o = 128; o > 0; o >>= 1) {
        if (t < o) red[t] += red[t + o];
        __syncthreads();
    }
    if (t == 0) bG[n] = red[0];
}

// bproj[h*32+r] = brf[h][r] + sum_dd b[h*64+dd]*Wrf[h][dd][r]
__global__ __launch_bounds__(256) void build_bproj(const float* __restrict__ b,
                                                   const float* __restrict__ Wrf,
                                                   const float* __restrict__ brf,
                                                   float* __restrict__ bout) {
    int c = blockIdx.x * 256 + threadIdx.x;
    if (c < 512) {
        int h = c >> 5, r = c & 31;
        float s = brf[c];
        for (int dd = 0; dd < 64; ++dd)
            s += b[h * 64 + dd] * Wrf[(size_t)(h * 64 + dd) * 32 + r];
        bout[c] = s;
    }
}

__global__ __launch_bounds__(256) void copy_vec(const float* __restrict__ src, float* __restrict__ dst, int n) {
    int i = blockIdx.x * 256 + threadIdx.x;
    if (i < n) dst[i] = src[i];
}

// ---------------------------------------------------------------------------
// fp16 hi/lo split conversions (lo pre-scaled by 2048 for fp16 normal range)
// ---------------------------------------------------------------------------
__global__ __launch_bounds__(256) void split_plain(const float* __restrict__ src,
        _Float16* __restrict__ hi, _Float16* __restrict__ lo, int n4) {
    int stride = gridDim.x * 256;
    for (int i = blockIdx.x * 256 + threadIdx.x; i < n4; i += stride) {
        float4 v = ((const float4*)src)[i];
        _Float16 h0 = (_Float16)v.x, h1 = (_Float16)v.y, h2 = (_Float16)v.z, h3 = (_Float16)v.w;
        ((half4v*)hi)[i] = (half4v){h0, h1, h2, h3};
        ((half4v*)lo)[i] = (half4v){(_Float16)((v.x - (float)h0) * 2048.0f),
                                    (_Float16)((v.y - (float)h1) * 2048.0f),
                                    (_Float16)((v.z - (float)h2) * 2048.0f),
                                    (_Float16)((v.w - (float)h3) * 2048.0f)};
    }
}

// transpose + split: src f32 [1024][N] -> hi/lo fp16 [N][1024]
__global__ __launch_bounds__(256) void split_T(const float* __restrict__ src, int N,
        _Float16* __restrict__ hi, _Float16* __restrict__ lo) {
    __shared__ float tile[32][33];
    int n0 = blockIdx.x * 32, k0 = blockIdx.y * 32;
    int t = threadIdx.x, tx = t & 31, ty = t >> 5;
    #pragma unroll
    for (int s = 0; s < 4; ++s)
        tile[ty + s * 8][tx] = src[(size_t)(k0 + ty + s * 8) * N + n0 + tx];
    __syncthreads();
    #pragma unroll
    for (int s = 0; s < 4; ++s) {
        int n = n0 + ty + s * 8;
        float v = tile[tx][ty + s * 8];
        _Float16 h = (_Float16)v;
        size_t o = (size_t)n * 1024 + k0 + tx;
        hi[o] = h;
        lo[o] = (_Float16)((v - (float)h) * 2048.0f);
    }
}

// ---------------------------------------------------------------------------
// MFMA GEMM, fp16 two-term split:  C = Ah*Bh + (Ah*Bl + Al*Bh)/2048 [+ bias]
// A: [M][K] hi/lo fp16, B: [N][K] hi/lo fp16.  Tile 128x128, 4 waves (2x2),
// BK=32.  LDS swizzle: cb_phys = cb ^ ((row>>1)&3) (64B rows, b128 reads ->
// 8 bank-groups x 2-way within each 16-lane group, disjoint across groups).
// global_load_lds keeps linear dest; source address carries the swizzle.
// ---------------------------------------------------------------------------
__device__ __forceinline__ void gemm_hilo_body(
    const _Float16* __restrict__ Ah, const _Float16* __restrict__ Al,
    const _Float16* __restrict__ Bh, const _Float16* __restrict__ Bl,
    const float* __restrict__ bias, float* __restrict__ Cout,
    int Ndim, int Kdim, int bx, int by, bool useBias)
{
    __shared__ _Float16 lds[16384];   // AH 0, AL 4096, BH 8192, BL 12288 (halves)
    const int t = threadIdx.x;
    const int w = t >> 6, l = t & 63;
    const int rowBase = by * 128;
    const int colBase = bx * 128;

    // staging: wave w stages rows [w*32, w*32+32); slots s = g*64+l
    const int rl0 = w * 32 + (l >> 2);
    const int rl1 = rl0 + 16;
    const int cb0 = (l & 3) ^ ((rl0 >> 1) & 3);
    const int cb1 = (l & 3) ^ ((rl1 >> 1) & 3);
    const size_t a0 = (size_t)(rowBase + rl0) * Kdim + cb0 * 8;
    const size_t a1 = (size_t)(rowBase + rl1) * Kdim + cb1 * 8;
    const size_t b0 = (size_t)(colBase + rl0) * Kdim + cb0 * 8;
    const size_t b1 = (size_t)(colBase + rl1) * Kdim + cb1 * 8;
    _Float16* dA0 = lds + w * 1024 + l * 8;
    _Float16* dA1 = dA0 + 512;

    // fragment offsets (halves), same swizzle
    const int wr = w >> 1, wc = w & 1;
    const int frow = l & 15, kb = l >> 4;
    int aoffs[4], boffs[4];
    #pragma unroll
    for (int i = 0; i < 4; ++i) {
        int ar = wr * 64 + i * 16 + frow;
        aoffs[i] = ar * 32 + ((kb ^ ((ar >> 1) & 3)) << 3);
    }
    #pragma unroll
    for (int j = 0; j < 4; ++j) {
        int br = wc * 64 + j * 16 + frow;
        boffs[j] = br * 32 + ((kb ^ ((br >> 1) & 3)) << 3);
    }

    f32x4 acc_h[4][4], acc_c[4][4];
    #pragma unroll
    for (int i = 0; i < 4; ++i)
        #pragma unroll
        for (int j = 0; j < 4; ++j) {
            acc_h[i][j] = (f32x4){0.0f, 0.0f, 0.0f, 0.0f};
            acc_c[i][j] = (f32x4){0.0f, 0.0f, 0.0f, 0.0f};
        }

    for (int k0 = 0; k0 < Kdim; k0 += 32) {
        __syncthreads();
        GLD16(Ah + a0 + k0, dA0);
        GLD16(Ah + a1 + k0, dA1);
        GLD16(Al + a0 + k0, dA0 + 4096);
        GLD16(Al + a1 + k0, dA1 + 4096);
        GLD16(Bh + b0 + k0, dA0 + 8192);
        GLD16(Bh + b1 + k0, dA1 + 8192);
        GLD16(Bl + b0 + k0, dA0 + 12288);
        GLD16(Bl + b1 + k0, dA1 + 12288);
        __syncthreads();
        half8 fah[4], fal[4], fbh[4], fbl[4];
        #pragma unroll
        for (int i = 0; i < 4; ++i) {
            fah[i] = *(const half8*)&lds[aoffs[i]];
            fal[i] = *(const half8*)&lds[4096 + aoffs[i]];
        }
        #pragma unroll
        for (int j = 0; j < 4; ++j) {
            fbh[j] = *(const half8*)&lds[8192 + boffs[j]];
            fbl[j] = *(const half8*)&lds[12288 + boffs[j]];
        }
        #pragma unroll
        for (int i = 0; i < 4; ++i)
            #pragma unroll
            for (int j = 0; j < 4; ++j) {
                acc_h[i][j] = __builtin_amdgcn_mfma_f32_16x16x32_f16(fah[i], fbh[j], acc_h[i][j], 0, 0, 0);
                acc_c[i][j] = __builtin_amdgcn_mfma_f32_16x16x32_f16(fah[i], fbl[j], acc_c[i][j], 0, 0, 0);
                acc_c[i][j] = __builtin_amdgcn_mfma_f32_16x16x32_f16(fal[i], fbh[j], acc_c[i][j], 0, 0, 0);
            }
    }

    #pragma unroll
    for (int i = 0; i < 4; ++i) {
        const int rg0 = rowBase + wr * 64 + i * 16 + (l >> 4) * 4;
        #pragma unroll
        for (int j = 0; j < 4; ++j) {
            const int cg = colBase + wc * 64 + j * 16 + frow;
            const float bb = useBias ? bias[cg] : 0.0f;
            #pragma unroll
            for (int r = 0; r < 4; ++r)
                Cout[(size_t)(rg0 + r) * Ndim + cg] = acc_h[i][j][r] + acc_c[i][j][r] * (1.0f / 2048.0f) + bb;
        }
    }
}

__device__ __forceinline__ void xcd_swz(int& bx, int& by) {
    int gx = gridDim.x;
    int n = gx * gridDim.y;
    int u = blockIdx.y * gx + blockIdx.x;
    if ((n & 7) == 0) {
        int c = n >> 3;
        u = (u & 7) * c + (u >> 3);
    }
    bx = u % gx;
    by = u / gx;
}

template<bool BIAS>
__global__ __launch_bounds__(256) void gemm_hilo(
    const _Float16* __restrict__ Ah, const _Float16* __restrict__ Al,
    const _Float16* __restrict__ Bh, const _Float16* __restrict__ Bl,
    const float* __restrict__ bias, float* __restrict__ Cout,
    int Ndim, int Kdim)
{
    int bx, by;
    xcd_swz(bx, by);
    gemm_hilo_body(Ah, Al, Bh, Bl, bias, Cout, Ndim, Kdim, bx, by, BIAS);
}

// z-batched over {Wq,Wk,Wv}: WtT[z][out][time] = sum_f W_z[out][f]*C_[time][f]
__global__ __launch_bounds__(256) void gemm_hilo3(
    const _Float16* __restrict__ W3h, const _Float16* __restrict__ W3l,
    const _Float16* __restrict__ Ch, const _Float16* __restrict__ Cl,
    float* __restrict__ WtT3)
{
    int z = blockIdx.z;
    gemm_hilo_body(W3h + (size_t)z * 1048576, W3l + (size_t)z * 1048576,
                   Ch, Cl, nullptr, WtT3 + (size_t)z * 1048576,
                   1024, 1024, blockIdx.x, blockIdx.y, false);
}

// ---------------------------------------------------------------------------
// WcatH/L[z*512+col][time] = split( sum_dd Wrf[h][dd][r] * WtT[z][h*64+dd][time] )
// col = h*32+r.  Coalesced reads and writes; hi/lo emitted directly.
// ---------------------------------------------------------------------------
__global__ __launch_bounds__(256) void projw_T(const float* __restrict__ WtT3,
        const float* __restrict__ Wrf,
        _Float16* __restrict__ WcH, _Float16* __restrict__ WcL) {
    int z = blockIdx.y;
    int col = blockIdx.x;
    int h = col >> 5, r = col & 31;
    __shared__ float wsh[64];
    int t = threadIdx.x;
    if (t < 64) wsh[t] = Wrf[(size_t)(h * 64 + t) * 32 + r];
    __syncthreads();
    const float* base = WtT3 + (size_t)z * 1048576 + (size_t)(h * 64) * 1024;
    float acc0 = 0.f, acc1 = 0.f, acc2 = 0.f, acc3 = 0.f;
    for (int dd = 0; dd < 64; ++dd) {
        float wv = wsh[dd];
        const float* row = base + (size_t)dd * 1024;
        acc0 = fmaf(wv, row[t], acc0);
        acc1 = fmaf(wv, row[t + 256], acc1);
        acc2 = fmaf(wv, row[t + 512], acc2);
        acc3 = fmaf(wv, row[t + 768], acc3);
    }
    size_t o = (size_t)(z * 512 + col) * 1024;
    float vals[4] = {acc0, acc1, acc2, acc3};
    #pragma unroll
    for (int q = 0; q < 4; ++q) {
        int f = t + q * 256;
        _Float16 hh = (_Float16)vals[q];
        WcH[o + f] = hh;
        WcL[o + f] = (_Float16)((vals[q] - (float)hh) * 2048.0f);
    }
}

// ---------------------------------------------------------------------------
// KV[bh][r][dd] = sum_m phi_k[m][r]*V[m][dd];  Ksum[bh][r] = sum_m phi_k[m][r]
// ---------------------------------------------------------------------------
__global__ __launch_bounds__(256) void kv_reduce(const float* __restrict__ PQV,
                                                 float* __restrict__ KV,
                                                 float* __restrict__ Ksum) {
    int bx = blockIdx.x;
    int bh = bx >> 3, ch = bx & 7;
    int b = bh >> 4, h = bh & 15;
    __shared__ float ps[4][64], vs[4][64];
    int tid = threadIdx.x;
    int r = tid >> 2, dd0 = (tid & 3) << 4;
    float acc[16] = {};
    float ks = 0.0f;
    int mstart = ch * 512;
    for (int m0 = mstart; m0 < mstart + 512; m0 += 4) {
        __syncthreads();
        if (tid < 128) {
            int rw = tid >> 5, cc = tid & 31;
            float praw = PQV[(size_t)(b * 4096 + m0 + rw) * 2048 + 512 + h * 32 + cc];
            float sv, cv;
            sincosf(praw, &sv, &cv);
            ps[rw][cc] = cv * INV_SQRT_RH;
            ps[rw][cc + 32] = sv * INV_SQRT_RH;
        } else {
            int ll = tid - 128;
            #pragma unroll
            for (int s = 0; s < 2; ++s) {
                int l2 = ll + s * 128;
                int rw = l2 >> 6, cc = l2 & 63;
                vs[rw][cc] = PQV[(size_t)(b * 4096 + m0 + rw) * 2048 + 1024 + h * 64 + cc];
            }
        }
        __syncthreads();
        #pragma unroll
        for (int mm = 0; mm < 4; ++mm) {
            float p = ps[mm][r];
            if ((tid & 3) == 0) ks += p;
            #pragma unroll
            for (int i = 0; i < 16; ++i) acc[i] = fmaf(p, vs[mm][dd0 + i], acc[i]);
        }
    }
    float* kvb = KV + ((size_t)bh << 12);
    #pragma unroll
    for (int i = 0; i < 16; ++i) atomicAdd(&kvb[(r << 6) + dd0 + i], acc[i]);
    if ((tid & 3) == 0) atomicAdd(&Ksum[(bh << 6) + r], ks);
}

// attn written directly as fp16 hi/lo (A-operand of the final MFMA GEMM)
__global__ __launch_bounds__(256) void attn_out(const float* __restrict__ PQV,
                                                const float* __restrict__ KV,
                                                const float* __restrict__ Ksum,
                                                _Float16* __restrict__ ah,
                                                _Float16* __restrict__ al) {
    int bh = blockIdx.x;
    int b = bh >> 4, h = bh & 15;
    int m0 = blockIdx.y << 5;
    __shared__ float KVs[64][64];
    __shared__ float Ks[64];
    __shared__ float ps[4][64];
    int tid = threadIdx.x;
    for (int l = tid; l < 4096; l += 256) KVs[l >> 6][l & 63] = KV[((size_t)bh << 12) + l];
    if (tid < 64) Ks[tid] = Ksum[(bh << 6) + tid];
    int rowi = tid >> 6, dd = tid & 63;
    for (int s = 0; s < 8; ++s) {
        __syncthreads();
        if (tid < 128) {
            int rw = tid >> 5, cc = tid & 31;
            float praw = PQV[(size_t)(b * 4096 + m0 + s * 4 + rw) * 2048 + h * 32 + cc];
            float sv, cv;
            sincosf(praw, &sv, &cv);
            ps[rw][cc] = cv * INV_SQRT_RH;
            ps[rw][cc + 32] = sv * INV_SQRT_RH;
        }
        __syncthreads();
        float num = 0.0f, den = 1e-6f;
        #pragma unroll
        for (int r = 0; r < 64; ++r) {
            float p = ps[rowi][r];
            num = fmaf(p, KVs[r][dd], num);
            den = fmaf(p, Ks[r], den);
        }
        int m = m0 + (s << 2) + rowi;
        float v = num / den;
        _Float16 hh = (_Float16)v;
        size_t o = (size_t)(b * 4096 + m) * 1024 + (h << 6) + dd;
        ah[o] = hh;
        al[o] = (_Float16)((v - (float)hh) * 2048.0f);
    }
}

extern "C" void kernel_launch(void* const* d_in, const int* in_sizes, int n_in,
                              void* d_out, int out_size, void* d_ws, size_t ws_size,
                              hipStream_t stream) {
    const float* x   = (const float*)d_in[0];
    const float* Wq  = (const float*)d_in[1];
    const float* bq  = (const float*)d_in[2];
    const float* Wk  = (const float*)d_in[3];
    const float* bk  = (const float*)d_in[4];
    const float* Wv  = (const float*)d_in[5];
    const float* bv  = (const float*)d_in[6];
    const float* Wp  = (const float*)d_in[7];
    const float* bp  = (const float*)d_in[8];
    const float* Wrf = (const float*)d_in[9];
    const float* brf = (const float*)d_in[10];
    float* out = (float*)d_out;
    float* ws  = (float*)d_ws;

    const size_t M1 = 1048576;
    // f32 region
    float* C_      = ws;                       // [1024 time][1024 freq]
    float* Gt      = ws + 1 * M1;              // [1024 time][1024 col]
    float* WtT3    = ws + 2 * M1;              // [3][1024 out][1024 time]
    float* WpGT_f  = ws + 5 * M1;              // [1024 time][1024 j]
    float* bias_cat= ws + 6 * M1;              // 2048
    float* bG      = ws + 6 * M1 + 2048;       // 1024
    float* KV      = ws + 6 * M1 + 8192;       // 262144
    float* Ksum    = KV + 262144;              // 4096
    float* PQV     = ws + 8 * M1;              // [16384][2048] = Pq|Pk|V (32M f32)

    // preproc-only halves (inside PQV's range; time-disjoint with it)
    _Float16* pre  = (_Float16*)(ws + 12 * M1);
    _Float16* Ch   = pre;                      // 1M halves each
    _Float16* Cl   = pre + 1 * M1;
    _Float16* Gth  = pre + 2 * M1;
    _Float16* Gtl  = pre + 3 * M1;
    _Float16* WpTh = pre + 4 * M1;
    _Float16* WpTl = pre + 5 * M1;
    _Float16* W3h  = pre + 6 * M1;             // 3M halves
    _Float16* W3l  = pre + 9 * M1;             // 3M halves

    // persistent halves
    _Float16* wsH   = (_Float16*)(ws + 40 * M1);
    _Float16* xh    = wsH;                     // 16M halves (reused as attn hi)
    _Float16* xl    = wsH + 16 * M1;           // (reused as attn lo)
    _Float16* WcatH = wsH + 32 * M1;           // [2048][1024]
    _Float16* WcatL = wsH + 34 * M1;
    _Float16* WpGTh = wsH + 36 * M1;           // [1024][1024]
    _Float16* WpGTl = wsH + 37 * M1;

    // --- DFT matrices + splits ---
    build_CG<<<8192, 256, 0, stream>>>(C_, Gt);
    split_plain<<<4096, 256, 0, stream>>>(x, xh, xl, 4194304);
    split_plain<<<1024, 256, 0, stream>>>(C_, Ch, Cl, 262144);
    split_plain<<<1024, 256, 0, stream>>>(Gt, Gth, Gtl, 262144);
    split_T<<<dim3(32, 32), 256, 0, stream>>>(Wp, 1024, WpTh, WpTl);
    split_plain<<<1024, 256, 0, stream>>>(Wq, W3h, W3l, 262144);
    split_plain<<<1024, 256, 0, stream>>>(Wk, W3h + 1048576, W3l + 1048576, 262144);
    split_plain<<<1024, 256, 0, stream>>>(Wv, W3h + 2097152, W3l + 2097152, 262144);

    // --- preprocessing GEMMs on matrix cores ---
    gemm_hilo3<<<dim3(8, 8, 3), 256, 0, stream>>>(W3h, W3l, Ch, Cl, WtT3);
    gemm_hilo<false><<<dim3(8, 8), 256, 0, stream>>>(Gth, Gtl, WpTh, WpTl, nullptr, WpGT_f, 1024, 1024);
    split_plain<<<1024, 256, 0, stream>>>(WpGT_f, WpGTh, WpGTl, 262144);
    projw_T<<<dim3(512, 2), 256, 0, stream>>>(WtT3, Wrf, WcatH, WcatL);
    split_plain<<<1024, 256, 0, stream>>>(WtT3 + 2 * M1, WcatH + 1048576, WcatL + 1048576, 262144);
    build_bproj<<<2, 256, 0, stream>>>(bq, Wrf, brf, bias_cat);
    build_bproj<<<2, 256, 0, stream>>>(bk, Wrf, brf, bias_cat + 512);
    copy_vec<<<4, 256, 0, stream>>>(bv, bias_cat + 1024, 1024);
    build_bG<<<1024, 256, 0, stream>>>(bp, Gt, bG);

    // --- heavy GEMM 1: PQV = x @ [WprojQ | WprojK | Wcv]^T + bias ---
    gemm_hilo<true><<<dim3(16, 128), 256, 0, stream>>>(xh, xl, WcatH, WcatL, bias_cat, PQV, 2048, 1024);

    // --- linear attention ---
    zero_kernel<<<(266240 + 255) / 256, 256, 0, stream>>>(KV, 266240);
    kv_reduce<<<512, 256, 0, stream>>>(PQV, KV, Ksum);
    attn_out<<<dim3(64, 128), 256, 0, stream>>>(PQV, KV, Ksum, xh, xl);

    // --- heavy GEMM 2: out = attn @ WpG + bG (irfft folded in) ---
    gemm_hilo<true><<<dim3(8, 128), 256, 0, stream>>>(xh, xl, WpGTh, WpGTl, bG, out, 1024, 1024);
}

// Round 6
// 900.644 us; speedup vs baseline: 1.2998x; 1.2998x over previous
//
#include <hip/hip_runtime.h>
#include <hip/hip_bf16.h>
#include <math.h>

// Problem sizes (fixed): B=4, M=4096, D=1024, H=16, d=64, R=64
#define BM 16384
#define INV_SQRT_RH 0.17677669529663687f

typedef _Float16 half8 __attribute__((ext_vector_type(8)));
typedef _Float16 half4v __attribute__((ext_vector_type(4)));
typedef float f32x4 __attribute__((ext_vector_type(4)));

#define GLD16(gp, lp) __builtin_amdgcn_global_load_lds((const __attribute__((address_space(1))) void*)(gp), (__attribute__((address_space(3))) void*)(lp), 16, 0, 0)

// ---------------------------------------------------------------------------
// DFT matrices.
// C_[n][j]: fx = x @ C_  (n = time index, j = freq-concat index)
// Gt[n][col] = G[col][n]: y = out2 @ G, stored transposed (B-operand layout)
// ---------------------------------------------------------------------------
__global__ __launch_bounds__(256) void build_CG(float* __restrict__ Cm, float* __restrict__ Gt) {
    int idx = blockIdx.x * 256 + threadIdx.x;
    const float w = 6.28318530717958647692f / 1024.0f;
    if (idx < 1048576) {
        int n = idx >> 10, j = idx & 1023;
        float val;
        if (j <= 512) {
            int red = (n * j) & 1023;
            val = cosf(red * w) * (1.0f / 1024.0f);
        } else {
            int tt = j - 513;
            int red = (n * tt) & 1023;
            val = sinf(red * w) * (1.0f / 1024.0f);
        }
        Cm[idx] = val;
    } else if (idx < 2097152) {
        int l = idx - 1048576;
        int n = l >> 10, col = l & 1023;
        float val;
        if (col < 512) {
            int red = (n * col) & 1023;
            val = (col == 0 ? 1.0f : 2.0f) * cosf(red * w);
        } else {
            int tt = col - 512;
            int red = (n * tt) & 1023;
            val = (tt == 0) ? 0.0f : 2.0f * sinf(red * w);
        }
        Gt[l] = val;
    }
}

__global__ __launch_bounds__(256) void zero_kernel(float* __restrict__ p, int n) {
    int i = blockIdx.x * 256 + threadIdx.x;
    if (i < n) p[i] = 0.0f;
}

// bG[n] = sum_col bp[col]*Gt[n][col]
__global__ __launch_bounds__(256) void build_bG(const float* __restrict__ bp,
                                                const float* __restrict__ Gt,
                                                float* __restrict__ bG) {
    int n = blockIdx.x, t = threadIdx.x;
    float s = 0.0f;
    for (int j = t; j < 1024; j += 256) s += bp[j] * Gt[(size_t)n * 1024 + j];
    __shared__ float red[256];
    red[t] = s;
    __syncthreads();
    for (int o = 128; o > 0; o >>= 1) {
        if (t < o) red[t] += red[t + o];
        __syncthreads();
    }
    if (t == 0) bG[n] = red[0];
}

// bproj[h*32+r] = brf[h][r] + sum_dd b[h*64+dd]*Wrf[h][dd][r]
__global__ __launch_bounds__(256) void build_bproj(const float* __restrict__ b,
                                                   const float* __restrict__ Wrf,
                                                   const float* __restrict__ brf,
                                                   float* __restrict__ bout) {
    int c = blockIdx.x * 256 + threadIdx.x;
    if (c < 512) {
        int h = c >> 5, r = c & 31;
        float s = brf[c];
        for (int dd = 0; dd < 64; ++dd)
            s += b[h * 64 + dd] * Wrf[(size_t)(h * 64 + dd) * 32 + r];
        bout[c] = s;
    }
}

__global__ __launch_bounds__(256) void copy_vec(const float* __restrict__ src, float* __restrict__ dst, int n) {
    int i = blockIdx.x * 256 + threadIdx.x;
    if (i < n) dst[i] = src[i];
}

// ---------------------------------------------------------------------------
// fp16 hi/lo split conversions.  lo is the UNSCALED residual (v - hi) so the
// three partial products Ah*Bh + Ah*Bl + Al*Bh can share ONE accumulator
// (keeps AGPR use at 64, under the 256-reg occupancy cliff).  Subnormal
// quantization of lo contributes <=3e-8 absolute per element -> ~1e-6 on
// outputs (threshold 1.1e-3).
// ---------------------------------------------------------------------------
__global__ __launch_bounds__(256) void split_plain(const float* __restrict__ src,
        _Float16* __restrict__ hi, _Float16* __restrict__ lo, int n4) {
    int stride = gridDim.x * 256;
    for (int i = blockIdx.x * 256 + threadIdx.x; i < n4; i += stride) {
        float4 v = ((const float4*)src)[i];
        _Float16 h0 = (_Float16)v.x, h1 = (_Float16)v.y, h2 = (_Float16)v.z, h3 = (_Float16)v.w;
        ((half4v*)hi)[i] = (half4v){h0, h1, h2, h3};
        ((half4v*)lo)[i] = (half4v){(_Float16)(v.x - (float)h0),
                                    (_Float16)(v.y - (float)h1),
                                    (_Float16)(v.z - (float)h2),
                                    (_Float16)(v.w - (float)h3)};
    }
}

// transpose + split: src f32 [1024][N] -> hi/lo fp16 [N][1024]
__global__ __launch_bounds__(256) void split_T(const float* __restrict__ src, int N,
        _Float16* __restrict__ hi, _Float16* __restrict__ lo) {
    __shared__ float tile[32][33];
    int n0 = blockIdx.x * 32, k0 = blockIdx.y * 32;
    int t = threadIdx.x, tx = t & 31, ty = t >> 5;
    #pragma unroll
    for (int s = 0; s < 4; ++s)
        tile[ty + s * 8][tx] = src[(size_t)(k0 + ty + s * 8) * N + n0 + tx];
    __syncthreads();
    #pragma unroll
    for (int s = 0; s < 4; ++s) {
        int n = n0 + ty + s * 8;
        float v = tile[tx][ty + s * 8];
        _Float16 h = (_Float16)v;
        size_t o = (size_t)n * 1024 + k0 + tx;
        hi[o] = h;
        lo[o] = (_Float16)(v - (float)h);
    }
}

// ---------------------------------------------------------------------------
// MFMA GEMM, fp16 split with single accumulator:
//   C = Ah*Bh + Ah*Bl + Al*Bh [+ bias]     (Al*Bl dropped, ~2^-22 relative)
// A: [M][K] hi/lo fp16, B: [N][K] hi/lo fp16.  Tile 128x128, 4 waves (2x2),
// BK=32.  LDS swizzle: cb_phys = cb ^ ((row>>1)&3); global_load_lds keeps a
// linear dest, the source address carries the swizzle (both-sides rule).
// 64 AGPR acc + ~70 VGPR frags -> 2 waves/SIMD (launch_bounds 256,2).
// ---------------------------------------------------------------------------
__device__ __forceinline__ void gemm_hilo_body(
    const _Float16* __restrict__ Ah, const _Float16* __restrict__ Al,
    const _Float16* __restrict__ Bh, const _Float16* __restrict__ Bl,
    const float* __restrict__ bias, float* __restrict__ Cout,
    int Ndim, int Kdim, int bx, int by, bool useBias)
{
    __shared__ _Float16 lds[16384];   // AH 0, AL 4096, BH 8192, BL 12288 (halves)
    const int t = threadIdx.x;
    const int w = t >> 6, l = t & 63;
    const int rowBase = by * 128;
    const int colBase = bx * 128;

    // staging: wave w stages rows [w*32, w*32+32)
    const int rl0 = w * 32 + (l >> 2);
    const int rl1 = rl0 + 16;
    const int cb0 = (l & 3) ^ ((rl0 >> 1) & 3);
    const int cb1 = (l & 3) ^ ((rl1 >> 1) & 3);
    const size_t a0 = (size_t)(rowBase + rl0) * Kdim + cb0 * 8;
    const size_t a1 = (size_t)(rowBase + rl1) * Kdim + cb1 * 8;
    const size_t b0 = (size_t)(colBase + rl0) * Kdim + cb0 * 8;
    const size_t b1 = (size_t)(colBase + rl1) * Kdim + cb1 * 8;
    _Float16* dA0 = lds + w * 1024 + l * 8;
    _Float16* dA1 = dA0 + 512;

    // fragment offsets (halves), same swizzle involution
    const int wr = w >> 1, wc = w & 1;
    const int frow = l & 15, kb = l >> 4;
    int aoffs[4], boffs[4];
    #pragma unroll
    for (int i = 0; i < 4; ++i) {
        int ar = wr * 64 + i * 16 + frow;
        aoffs[i] = ar * 32 + ((kb ^ ((ar >> 1) & 3)) << 3);
    }
    #pragma unroll
    for (int j = 0; j < 4; ++j) {
        int br = wc * 64 + j * 16 + frow;
        boffs[j] = br * 32 + ((kb ^ ((br >> 1) & 3)) << 3);
    }

    f32x4 acc[4][4];
    #pragma unroll
    for (int i = 0; i < 4; ++i)
        #pragma unroll
        for (int j = 0; j < 4; ++j)
            acc[i][j] = (f32x4){0.0f, 0.0f, 0.0f, 0.0f};

    for (int k0 = 0; k0 < Kdim; k0 += 32) {
        __syncthreads();
        GLD16(Ah + a0 + k0, dA0);
        GLD16(Ah + a1 + k0, dA1);
        GLD16(Al + a0 + k0, dA0 + 4096);
        GLD16(Al + a1 + k0, dA1 + 4096);
        GLD16(Bh + b0 + k0, dA0 + 8192);
        GLD16(Bh + b1 + k0, dA1 + 8192);
        GLD16(Bl + b0 + k0, dA0 + 12288);
        GLD16(Bl + b1 + k0, dA1 + 12288);
        __syncthreads();
        half8 fah[4], fal[4], fbh[4], fbl[4];
        #pragma unroll
        for (int i = 0; i < 4; ++i) {
            fah[i] = *(const half8*)&lds[aoffs[i]];
            fal[i] = *(const half8*)&lds[4096 + aoffs[i]];
        }
        #pragma unroll
        for (int j = 0; j < 4; ++j) {
            fbh[j] = *(const half8*)&lds[8192 + boffs[j]];
            fbl[j] = *(const half8*)&lds[12288 + boffs[j]];
        }
        #pragma unroll
        for (int i = 0; i < 4; ++i)
            #pragma unroll
            for (int j = 0; j < 4; ++j) {
                acc[i][j] = __builtin_amdgcn_mfma_f32_16x16x32_f16(fah[i], fbh[j], acc[i][j], 0, 0, 0);
                acc[i][j] = __builtin_amdgcn_mfma_f32_16x16x32_f16(fah[i], fbl[j], acc[i][j], 0, 0, 0);
                acc[i][j] = __builtin_amdgcn_mfma_f32_16x16x32_f16(fal[i], fbh[j], acc[i][j], 0, 0, 0);
            }
    }

    #pragma unroll
    for (int i = 0; i < 4; ++i) {
        const int rg0 = rowBase + wr * 64 + i * 16 + (l >> 4) * 4;
        #pragma unroll
        for (int j = 0; j < 4; ++j) {
            const int cg = colBase + wc * 64 + j * 16 + frow;
            const float bb = useBias ? bias[cg] : 0.0f;
            #pragma unroll
            for (int r = 0; r < 4; ++r)
                Cout[(size_t)(rg0 + r) * Ndim + cg] = acc[i][j][r] + bb;
        }
    }
}

__device__ __forceinline__ void xcd_swz(int& bx, int& by) {
    int gx = gridDim.x;
    int n = gx * gridDim.y;
    int u = blockIdx.y * gx + blockIdx.x;
    if ((n & 7) == 0) {
        int c = n >> 3;
        u = (u & 7) * c + (u >> 3);
    }
    bx = u % gx;
    by = u / gx;
}

template<bool BIAS>
__global__ __launch_bounds__(256, 2) void gemm_hilo(
    const _Float16* __restrict__ Ah, const _Float16* __restrict__ Al,
    const _Float16* __restrict__ Bh, const _Float16* __restrict__ Bl,
    const float* __restrict__ bias, float* __restrict__ Cout,
    int Ndim, int Kdim)
{
    int bx, by;
    xcd_swz(bx, by);
    gemm_hilo_body(Ah, Al, Bh, Bl, bias, Cout, Ndim, Kdim, bx, by, BIAS);
}

// z-batched over {Wq,Wk,Wv}: WtT[z][out][time] = sum_f W_z[out][f]*C_[time][f]
__global__ __launch_bounds__(256, 2) void gemm_hilo3(
    const _Float16* __restrict__ W3h, const _Float16* __restrict__ W3l,
    const _Float16* __restrict__ Ch, const _Float16* __restrict__ Cl,
    float* __restrict__ WtT3)
{
    int z = blockIdx.z;
    gemm_hilo_body(W3h + (size_t)z * 1048576, W3l + (size_t)z * 1048576,
                   Ch, Cl, nullptr, WtT3 + (size_t)z * 1048576,
                   1024, 1024, blockIdx.x, blockIdx.y, false);
}

// ---------------------------------------------------------------------------
// WcatH/L[z*512+col][time] = split( sum_dd Wrf[h][dd][r] * WtT[z][h*64+dd][time] )
// col = h*32+r.  Coalesced reads and writes; hi/lo emitted directly.
// ---------------------------------------------------------------------------
__global__ __launch_bounds__(256) void projw_T(const float* __restrict__ WtT3,
        const float* __restrict__ Wrf,
        _Float16* __restrict__ WcH, _Float16* __restrict__ WcL) {
    int z = blockIdx.y;
    int col = blockIdx.x;
    int h = col >> 5, r = col & 31;
    __shared__ float wsh[64];
    int t = threadIdx.x;
    if (t < 64) wsh[t] = Wrf[(size_t)(h * 64 + t) * 32 + r];
    __syncthreads();
    const float* base = WtT3 + (size_t)z * 1048576 + (size_t)(h * 64) * 1024;
    float acc0 = 0.f, acc1 = 0.f, acc2 = 0.f, acc3 = 0.f;
    for (int dd = 0; dd < 64; ++dd) {
        float wv = wsh[dd];
        const float* row = base + (size_t)dd * 1024;
        acc0 = fmaf(wv, row[t], acc0);
        acc1 = fmaf(wv, row[t + 256], acc1);
        acc2 = fmaf(wv, row[t + 512], acc2);
        acc3 = fmaf(wv, row[t + 768], acc3);
    }
    size_t o = (size_t)(z * 512 + col) * 1024;
    float vals[4] = {acc0, acc1, acc2, acc3};
    #pragma unroll
    for (int q = 0; q < 4; ++q) {
        int f = t + q * 256;
        _Float16 hh = (_Float16)vals[q];
        WcH[o + f] = hh;
        WcL[o + f] = (_Float16)(vals[q] - (float)hh);
    }
}

// ---------------------------------------------------------------------------
// KV[bh][r][dd] = sum_m phi_k[m][r]*V[m][dd];  Ksum[bh][r] = sum_m phi_k[m][r]
// ---------------------------------------------------------------------------
__global__ __launch_bounds__(256) void kv_reduce(const float* __restrict__ PQV,
                                                 float* __restrict__ KV,
                                                 float* __restrict__ Ksum) {
    int bx = blockIdx.x;
    int bh = bx >> 3, ch = bx & 7;
    int b = bh >> 4, h = bh & 15;
    __shared__ float ps[4][64], vs[4][64];
    int tid = threadIdx.x;
    int r = tid >> 2, dd0 = (tid & 3) << 4;
    float acc[16] = {};
    float ks = 0.0f;
    int mstart = ch * 512;
    for (int m0 = mstart; m0 < mstart + 512; m0 += 4) {
        __syncthreads();
        if (tid < 128) {
            int rw = tid >> 5, cc = tid & 31;
            float praw = PQV[(size_t)(b * 4096 + m0 + rw) * 2048 + 512 + h * 32 + cc];
            float sv, cv;
            sincosf(praw, &sv, &cv);
            ps[rw][cc] = cv * INV_SQRT_RH;
            ps[rw][cc + 32] = sv * INV_SQRT_RH;
        } else {
            int ll = tid - 128;
            #pragma unroll
            for (int s = 0; s < 2; ++s) {
                int l2 = ll + s * 128;
                int rw = l2 >> 6, cc = l2 & 63;
                vs[rw][cc] = PQV[(size_t)(b * 4096 + m0 + rw) * 2048 + 1024 + h * 64 + cc];
            }
        }
        __syncthreads();
        #pragma unroll
        for (int mm = 0; mm < 4; ++mm) {
            float p = ps[mm][r];
            if ((tid & 3) == 0) ks += p;
            #pragma unroll
            for (int i = 0; i < 16; ++i) acc[i] = fmaf(p, vs[mm][dd0 + i], acc[i]);
        }
    }
    float* kvb = KV + ((size_t)bh << 12);
    #pragma unroll
    for (int i = 0; i < 16; ++i) atomicAdd(&kvb[(r << 6) + dd0 + i], acc[i]);
    if ((tid & 3) == 0) atomicAdd(&Ksum[(bh << 6) + r], ks);
}

// attn written directly as fp16 hi/lo (A-operand of the final MFMA GEMM)
__global__ __launch_bounds__(256) void attn_out(const float* __restrict__ PQV,
                                                const float* __restrict__ KV,
                                                const float* __restrict__ Ksum,
                                                _Float16* __restrict__ ah,
                                                _Float16* __restrict__ al) {
    int bh = blockIdx.x;
    int b = bh >> 4, h = bh & 15;
    int m0 = blockIdx.y << 5;
    __shared__ float KVs[64][64];
    __shared__ float Ks[64];
    __shared__ float ps[4][64];
    int tid = threadIdx.x;
    for (int l = tid; l < 4096; l += 256) KVs[l >> 6][l & 63] = KV[((size_t)bh << 12) + l];
    if (tid < 64) Ks[tid] = Ksum[(bh << 6) + tid];
    int rowi = tid >> 6, dd = tid & 63;
    for (int s = 0; s < 8; ++s) {
        __syncthreads();
        if (tid < 128) {
            int rw = tid >> 5, cc = tid & 31;
            float praw = PQV[(size_t)(b * 4096 + m0 + s * 4 + rw) * 2048 + h * 32 + cc];
            float sv, cv;
            sincosf(praw, &sv, &cv);
            ps[rw][cc] = cv * INV_SQRT_RH;
            ps[rw][cc + 32] = sv * INV_SQRT_RH;
        }
        __syncthreads();
        float num = 0.0f, den = 1e-6f;
        #pragma unroll
        for (int r = 0; r < 64; ++r) {
            float p = ps[rowi][r];
            num = fmaf(p, KVs[r][dd], num);
            den = fmaf(p, Ks[r], den);
        }
        int m = m0 + (s << 2) + rowi;
        float v = num / den;
        _Float16 hh = (_Float16)v;
        size_t o = (size_t)(b * 4096 + m) * 1024 + (h << 6) + dd;
        ah[o] = hh;
        al[o] = (_Float16)(v - (float)hh);
    }
}

extern "C" void kernel_launch(void* const* d_in, const int* in_sizes, int n_in,
                              void* d_out, int out_size, void* d_ws, size_t ws_size,
                              hipStream_t stream) {
    const float* x   = (const float*)d_in[0];
    const float* Wq  = (const float*)d_in[1];
    const float* bq  = (const float*)d_in[2];
    const float* Wk  = (const float*)d_in[3];
    const float* bk  = (const float*)d_in[4];
    const float* Wv  = (const float*)d_in[5];
    const float* bv  = (const float*)d_in[6];
    const float* Wp  = (const float*)d_in[7];
    const float* bp  = (const float*)d_in[8];
    const float* Wrf = (const float*)d_in[9];
    const float* brf = (const float*)d_in[10];
    float* out = (float*)d_out;
    float* ws  = (float*)d_ws;

    const size_t M1 = 1048576;
    // f32 region
    float* C_      = ws;                       // [1024 time][1024 freq]
    float* Gt      = ws + 1 * M1;              // [1024 time][1024 col]
    float* WtT3    = ws + 2 * M1;              // [3][1024 out][1024 time]
    float* WpGT_f  = ws + 5 * M1;              // [1024 time][1024 j]
    float* bias_cat= ws + 6 * M1;              // 2048
    float* bG      = ws + 6 * M1 + 2048;       // 1024
    float* KV      = ws + 6 * M1 + 8192;       // 262144
    float* Ksum    = KV + 262144;              // 4096
    float* PQV     = ws + 8 * M1;              // [16384][2048] = Pq|Pk|V (32M f32)

    // preproc-only halves (inside PQV's range; time-disjoint with it)
    _Float16* pre  = (_Float16*)(ws + 12 * M1);
    _Float16* Ch   = pre;                      // 1M halves each
    _Float16* Cl   = pre + 1 * M1;
    _Float16* Gth  = pre + 2 * M1;
    _Float16* Gtl  = pre + 3 * M1;
    _Float16* WpTh = pre + 4 * M1;
    _Float16* WpTl = pre + 5 * M1;
    _Float16* W3h  = pre + 6 * M1;             // 3M halves
    _Float16* W3l  = pre + 9 * M1;             // 3M halves

    // persistent halves
    _Float16* wsH   = (_Float16*)(ws + 40 * M1);
    _Float16* xh    = wsH;                     // 16M halves (reused as attn hi)
    _Float16* xl    = wsH + 16 * M1;           // (reused as attn lo)
    _Float16* WcatH = wsH + 32 * M1;           // [2048][1024]
    _Float16* WcatL = wsH + 34 * M1;
    _Float16* WpGTh = wsH + 36 * M1;           // [1024][1024]
    _Float16* WpGTl = wsH + 37 * M1;

    // --- DFT matrices + splits ---
    build_CG<<<8192, 256, 0, stream>>>(C_, Gt);
    split_plain<<<4096, 256, 0, stream>>>(x, xh, xl, 4194304);
    split_plain<<<1024, 256, 0, stream>>>(C_, Ch, Cl, 262144);
    split_plain<<<1024, 256, 0, stream>>>(Gt, Gth, Gtl, 262144);
    split_T<<<dim3(32, 32), 256, 0, stream>>>(Wp, 1024, WpTh, WpTl);
    split_plain<<<1024, 256, 0, stream>>>(Wq, W3h, W3l, 262144);
    split_plain<<<1024, 256, 0, stream>>>(Wk, W3h + 1048576, W3l + 1048576, 262144);
    split_plain<<<1024, 256, 0, stream>>>(Wv, W3h + 2097152, W3l + 2097152, 262144);

    // --- preprocessing GEMMs on matrix cores ---
    gemm_hilo3<<<dim3(8, 8, 3), 256, 0, stream>>>(W3h, W3l, Ch, Cl, WtT3);
    gemm_hilo<false><<<dim3(8, 8), 256, 0, stream>>>(Gth, Gtl, WpTh, WpTl, nullptr, WpGT_f, 1024, 1024);
    split_plain<<<1024, 256, 0, stream>>>(WpGT_f, WpGTh, WpGTl, 262144);
    projw_T<<<dim3(512, 2), 256, 0, stream>>>(WtT3, Wrf, WcatH, WcatL);
    split_plain<<<1024, 256, 0, stream>>>(WtT3 + 2 * M1, WcatH + 1048576, WcatL + 1048576, 262144);
    build_bproj<<<2, 256, 0, stream>>>(bq, Wrf, brf, bias_cat);
    build_bproj<<<2, 256, 0, stream>>>(bk, Wrf, brf, bias_cat + 512);
    copy_vec<<<4, 256, 0, stream>>>(bv, bias_cat + 1024, 1024);
    build_bG<<<1024, 256, 0, stream>>>(bp, Gt, bG);

    // --- heavy GEMM 1: PQV = x @ [WprojQ | WprojK | Wcv]^T + bias ---
    gemm_hilo<true><<<dim3(16, 128), 256, 0, stream>>>(xh, xl, WcatH, WcatL, bias_cat, PQV, 2048, 1024);

    // --- linear attention ---
    zero_kernel<<<(266240 + 255) / 256, 256, 0, stream>>>(KV, 266240);
    kv_reduce<<<512, 256, 0, stream>>>(PQV, KV, Ksum);
    attn_out<<<dim3(64, 128), 256, 0, stream>>>(PQV, KV, Ksum, xh, xl);

    // --- heavy GEMM 2: out = attn @ WpG + bG (irfft folded in) ---
    gemm_hilo<true><<<dim3(8, 128), 256, 0, stream>>>(xh, xl, WpGTh, WpGTl, bG, out, 1024, 1024);
}

// Round 8
// 676.844 us; speedup vs baseline: 1.7296x; 1.3307x over previous
//
#include <hip/hip_runtime.h>
#include <hip/hip_bf16.h>
#include <math.h>

// Problem sizes (fixed): B=4, M=4096, D=1024, H=16, d=64, R=64
#define BM 16384
#define INV_SQRT_RH 0.17677669529663687f

typedef _Float16 half8 __attribute__((ext_vector_type(8)));
typedef _Float16 half4v __attribute__((ext_vector_type(4)));
typedef float f32x4 __attribute__((ext_vector_type(4)));

#define GLD16(gp, lp) __builtin_amdgcn_global_load_lds((const __attribute__((address_space(1))) void*)(gp), (__attribute__((address_space(3))) void*)(lp), 16, 0, 0)

// ---------------------------------------------------------------------------
// DFT matrices. C_[n][j]: fx = x @ C_.  Gt[n][col] = G[col][n] (irfft, B-layout)
// ---------------------------------------------------------------------------
__global__ __launch_bounds__(256) void build_CG(float* __restrict__ Cm, float* __restrict__ Gt) {
    int idx = blockIdx.x * 256 + threadIdx.x;
    const float w = 6.28318530717958647692f / 1024.0f;
    if (idx < 1048576) {
        int n = idx >> 10, j = idx & 1023;
        float val;
        if (j <= 512) {
            int red = (n * j) & 1023;
            val = cosf(red * w) * (1.0f / 1024.0f);
        } else {
            int tt = j - 513;
            int red = (n * tt) & 1023;
            val = sinf(red * w) * (1.0f / 1024.0f);
        }
        Cm[idx] = val;
    } else if (idx < 2097152) {
        int l = idx - 1048576;
        int n = l >> 10, col = l & 1023;
        float val;
        if (col < 512) {
            int red = (n * col) & 1023;
            val = (col == 0 ? 1.0f : 2.0f) * cosf(red * w);
        } else {
            int tt = col - 512;
            int red = (n * tt) & 1023;
            val = (tt == 0) ? 0.0f : 2.0f * sinf(red * w);
        }
        Gt[l] = val;
    }
}

__global__ __launch_bounds__(256) void zero_kernel(float* __restrict__ p, int n) {
    int i = blockIdx.x * 256 + threadIdx.x;
    if (i < n) p[i] = 0.0f;
}

__global__ __launch_bounds__(256) void build_bG(const float* __restrict__ bp,
                                                const float* __restrict__ Gt,
                                                float* __restrict__ bG) {
    int n = blockIdx.x, t = threadIdx.x;
    float s = 0.0f;
    for (int j = t; j < 1024; j += 256) s += bp[j] * Gt[(size_t)n * 1024 + j];
    __shared__ float red[256];
    red[t] = s;
    __syncthreads();
    for (int o = 128; o > 0; o >>= 1) {
        if (t < o) red[t] += red[t + o];
        __syncthreads();
    }
    if (t == 0) bG[n] = red[0];
}

__global__ __launch_bounds__(256) void build_bproj(const float* __restrict__ b,
                                                   const float* __restrict__ Wrf,
                                                   const float* __restrict__ brf,
                                                   float* __restrict__ bout) {
    int c = blockIdx.x * 256 + threadIdx.x;
    if (c < 512) {
        int h = c >> 5, r = c & 31;
        float s = brf[c];
        for (int dd = 0; dd < 64; ++dd)
            s += b[h * 64 + dd] * Wrf[(size_t)(h * 64 + dd) * 32 + r];
        bout[c] = s;
    }
}

__global__ __launch_bounds__(256) void copy_vec(const float* __restrict__ src, float* __restrict__ dst, int n) {
    int i = blockIdx.x * 256 + threadIdx.x;
    if (i < n) dst[i] = src[i];
}

// ---------------------------------------------------------------------------
// fp16 hi/lo split (lo = unscaled residual; single-accumulator 3-term MFMA)
// ---------------------------------------------------------------------------
__global__ __launch_bounds__(256) void split_plain(const float* __restrict__ src,
        _Float16* __restrict__ hi, _Float16* __restrict__ lo, int n4) {
    int stride = gridDim.x * 256;
    for (int i = blockIdx.x * 256 + threadIdx.x; i < n4; i += stride) {
        float4 v = ((const float4*)src)[i];
        _Float16 h0 = (_Float16)v.x, h1 = (_Float16)v.y, h2 = (_Float16)v.z, h3 = (_Float16)v.w;
        ((half4v*)hi)[i] = (half4v){h0, h1, h2, h3};
        ((half4v*)lo)[i] = (half4v){(_Float16)(v.x - (float)h0),
                                    (_Float16)(v.y - (float)h1),
                                    (_Float16)(v.z - (float)h2),
                                    (_Float16)(v.w - (float)h3)};
    }
}

// transpose + split: src f32 [1024][N] -> hi/lo fp16 [N][1024]
__global__ __launch_bounds__(256) void split_T(const float* __restrict__ src, int N,
        _Float16* __restrict__ hi, _Float16* __restrict__ lo) {
    __shared__ float tile[32][33];
    int n0 = blockIdx.x * 32, k0 = blockIdx.y * 32;
    int t = threadIdx.x, tx = t & 31, ty = t >> 5;
    #pragma unroll
    for (int s = 0; s < 4; ++s)
        tile[ty + s * 8][tx] = src[(size_t)(k0 + ty + s * 8) * N + n0 + tx];
    __syncthreads();
    #pragma unroll
    for (int s = 0; s < 4; ++s) {
        int n = n0 + ty + s * 8;
        float v = tile[tx][ty + s * 8];
        _Float16 h = (_Float16)v;
        size_t o = (size_t)n * 1024 + k0 + tx;
        hi[o] = h;
        lo[o] = (_Float16)(v - (float)h);
    }
}

// ---------------------------------------------------------------------------
// MFMA GEMM, 3-term single-acc: C = Ah*Bh + Ah*Bl + Al*Bh [+ colbias]
// Tile 128x128, 4 waves, BK=32, LDS swizzle cb^((row>>1)&3) both sides.
// ---------------------------------------------------------------------------
__device__ __forceinline__ void gemm_hilo_body(
    const _Float16* __restrict__ Ah, const _Float16* __restrict__ Al,
    const _Float16* __restrict__ Bh, const _Float16* __restrict__ Bl,
    const float* __restrict__ bias, float* __restrict__ Cout,
    int Ndim, int Kdim, int bx, int by, bool useBias)
{
    __shared__ _Float16 lds[16384];   // AH 0, AL 4096, BH 8192, BL 12288
    const int t = threadIdx.x;
    const int w = t >> 6, l = t & 63;
    const int rowBase = by * 128;
    const int colBase = bx * 128;

    const int rl0 = w * 32 + (l >> 2);
    const int rl1 = rl0 + 16;
    const int cb0 = (l & 3) ^ ((rl0 >> 1) & 3);
    const int cb1 = (l & 3) ^ ((rl1 >> 1) & 3);
    const size_t a0 = (size_t)(rowBase + rl0) * Kdim + cb0 * 8;
    const size_t a1 = (size_t)(rowBase + rl1) * Kdim + cb1 * 8;
    const size_t b0 = (size_t)(colBase + rl0) * Kdim + cb0 * 8;
    const size_t b1 = (size_t)(colBase + rl1) * Kdim + cb1 * 8;
    _Float16* dA0 = lds + w * 1024 + l * 8;
    _Float16* dA1 = dA0 + 512;

    const int wr = w >> 1, wc = w & 1;
    const int frow = l & 15, kb = l >> 4;
    int aoffs[4], boffs[4];
    #pragma unroll
    for (int i = 0; i < 4; ++i) {
        int ar = wr * 64 + i * 16 + frow;
        aoffs[i] = ar * 32 + ((kb ^ ((ar >> 1) & 3)) << 3);
    }
    #pragma unroll
    for (int j = 0; j < 4; ++j) {
        int br = wc * 64 + j * 16 + frow;
        boffs[j] = br * 32 + ((kb ^ ((br >> 1) & 3)) << 3);
    }

    f32x4 acc[4][4];
    #pragma unroll
    for (int i = 0; i < 4; ++i)
        #pragma unroll
        for (int j = 0; j < 4; ++j)
            acc[i][j] = (f32x4){0.0f, 0.0f, 0.0f, 0.0f};

    for (int k0 = 0; k0 < Kdim; k0 += 32) {
        __syncthreads();
        GLD16(Ah + a0 + k0, dA0);
        GLD16(Ah + a1 + k0, dA1);
        GLD16(Al + a0 + k0, dA0 + 4096);
        GLD16(Al + a1 + k0, dA1 + 4096);
        GLD16(Bh + b0 + k0, dA0 + 8192);
        GLD16(Bh + b1 + k0, dA1 + 8192);
        GLD16(Bl + b0 + k0, dA0 + 12288);
        GLD16(Bl + b1 + k0, dA1 + 12288);
        __syncthreads();
        half8 fah[4], fal[4], fbh[4], fbl[4];
        #pragma unroll
        for (int i = 0; i < 4; ++i) {
            fah[i] = *(const half8*)&lds[aoffs[i]];
            fal[i] = *(const half8*)&lds[4096 + aoffs[i]];
        }
        #pragma unroll
        for (int j = 0; j < 4; ++j) {
            fbh[j] = *(const half8*)&lds[8192 + boffs[j]];
            fbl[j] = *(const half8*)&lds[12288 + boffs[j]];
        }
        #pragma unroll
        for (int i = 0; i < 4; ++i)
            #pragma unroll
            for (int j = 0; j < 4; ++j) {
                acc[i][j] = __builtin_amdgcn_mfma_f32_16x16x32_f16(fah[i], fbh[j], acc[i][j], 0, 0, 0);
                acc[i][j] = __builtin_amdgcn_mfma_f32_16x16x32_f16(fah[i], fbl[j], acc[i][j], 0, 0, 0);
                acc[i][j] = __builtin_amdgcn_mfma_f32_16x16x32_f16(fal[i], fbh[j], acc[i][j], 0, 0, 0);
            }
    }

    #pragma unroll
    for (int i = 0; i < 4; ++i) {
        const int rg0 = rowBase + wr * 64 + i * 16 + (l >> 4) * 4;
        #pragma unroll
        for (int j = 0; j < 4; ++j) {
            const int cg = colBase + wc * 64 + j * 16 + frow;
            const float bb = useBias ? bias[cg] : 0.0f;
            #pragma unroll
            for (int r = 0; r < 4; ++r)
                Cout[(size_t)(rg0 + r) * Ndim + cg] = acc[i][j][r] + bb;
        }
    }
}

__device__ __forceinline__ void xcd_swz(int& bx, int& by) {
    int gx = gridDim.x;
    int n = gx * gridDim.y;
    int u = blockIdx.y * gx + blockIdx.x;
    if ((n & 7) == 0) {
        int c = n >> 3;
        u = (u & 7) * c + (u >> 3);
    }
    bx = u % gx;
    by = u / gx;
}

template<bool BIAS>
__global__ __launch_bounds__(256, 2) void gemm_hilo(
    const _Float16* __restrict__ Ah, const _Float16* __restrict__ Al,
    const _Float16* __restrict__ Bh, const _Float16* __restrict__ Bl,
    const float* __restrict__ bias, float* __restrict__ Cout,
    int Ndim, int Kdim)
{
    int bx, by;
    xcd_swz(bx, by);
    gemm_hilo_body(Ah, Al, Bh, Bl, bias, Cout, Ndim, Kdim, bx, by, BIAS);
}

// z-batched over {Wq,Wk,Wv}: WtT[z][out][time] = sum_f W_z[out][f]*C_[time][f]
__global__ __launch_bounds__(256, 2) void gemm_hilo3(
    const _Float16* __restrict__ W3h, const _Float16* __restrict__ W3l,
    const _Float16* __restrict__ Ch, const _Float16* __restrict__ Cl,
    float* __restrict__ WtT3)
{
    int z = blockIdx.z;
    gemm_hilo_body(W3h + (size_t)z * 1048576, W3l + (size_t)z * 1048576,
                   Ch, Cl, nullptr, WtT3 + (size_t)z * 1048576,
                   1024, 1024, blockIdx.x, blockIdx.y, false);
}

// ---------------------------------------------------------------------------
// GEMM1b: [Pkt | Vt] = Wcat[512..2047] @ x^T, ROW-bias, mixed epilogue:
// rows<512 -> f32 Pkt[row][m]; rows>=512 -> fp16 hi/lo Vt[row-512][m].
// ---------------------------------------------------------------------------
__global__ __launch_bounds__(256, 2) void gemm_pkvt(
    const _Float16* __restrict__ Ah, const _Float16* __restrict__ Al,
    const _Float16* __restrict__ Bh, const _Float16* __restrict__ Bl,
    const float* __restrict__ rowbias, float* __restrict__ Pkt,
    _Float16* __restrict__ VtH, _Float16* __restrict__ VtL)
{
    int bx, by;
    xcd_swz(bx, by);
    const int Kdim = 1024;
    __shared__ _Float16 lds[16384];
    const int t = threadIdx.x;
    const int w = t >> 6, l = t & 63;
    const int rowBase = by * 128;
    const int colBase = bx * 128;

    const int rl0 = w * 32 + (l >> 2);
    const int rl1 = rl0 + 16;
    const int cb0 = (l & 3) ^ ((rl0 >> 1) & 3);
    const int cb1 = (l & 3) ^ ((rl1 >> 1) & 3);
    const size_t a0 = (size_t)(rowBase + rl0) * Kdim + cb0 * 8;
    const size_t a1 = (size_t)(rowBase + rl1) * Kdim + cb1 * 8;
    const size_t b0 = (size_t)(colBase + rl0) * Kdim + cb0 * 8;
    const size_t b1 = (size_t)(colBase + rl1) * Kdim + cb1 * 8;
    _Float16* dA0 = lds + w * 1024 + l * 8;
    _Float16* dA1 = dA0 + 512;

    const int wr = w >> 1, wc = w & 1;
    const int frow = l & 15, kb = l >> 4;
    int aoffs[4], boffs[4];
    #pragma unroll
    for (int i = 0; i < 4; ++i) {
        int ar = wr * 64 + i * 16 + frow;
        aoffs[i] = ar * 32 + ((kb ^ ((ar >> 1) & 3)) << 3);
    }
    #pragma unroll
    for (int j = 0; j < 4; ++j) {
        int br = wc * 64 + j * 16 + frow;
        boffs[j] = br * 32 + ((kb ^ ((br >> 1) & 3)) << 3);
    }

    f32x4 acc[4][4];
    #pragma unroll
    for (int i = 0; i < 4; ++i)
        #pragma unroll
        for (int j = 0; j < 4; ++j)
            acc[i][j] = (f32x4){0.0f, 0.0f, 0.0f, 0.0f};

    for (int k0 = 0; k0 < Kdim; k0 += 32) {
        __syncthreads();
        GLD16(Ah + a0 + k0, dA0);
        GLD16(Ah + a1 + k0, dA1);
        GLD16(Al + a0 + k0, dA0 + 4096);
        GLD16(Al + a1 + k0, dA1 + 4096);
        GLD16(Bh + b0 + k0, dA0 + 8192);
        GLD16(Bh + b1 + k0, dA1 + 8192);
        GLD16(Bl + b0 + k0, dA0 + 12288);
        GLD16(Bl + b1 + k0, dA1 + 12288);
        __syncthreads();
        half8 fah[4], fal[4], fbh[4], fbl[4];
        #pragma unroll
        for (int i = 0; i < 4; ++i) {
            fah[i] = *(const half8*)&lds[aoffs[i]];
            fal[i] = *(const half8*)&lds[4096 + aoffs[i]];
        }
        #pragma unroll
        for (int j = 0; j < 4; ++j) {
            fbh[j] = *(const half8*)&lds[8192 + boffs[j]];
            fbl[j] = *(const half8*)&lds[12288 + boffs[j]];
        }
        #pragma unroll
        for (int i = 0; i < 4; ++i)
            #pragma unroll
            for (int j = 0; j < 4; ++j) {
                acc[i][j] = __builtin_amdgcn_mfma_f32_16x16x32_f16(fah[i], fbh[j], acc[i][j], 0, 0, 0);
                acc[i][j] = __builtin_amdgcn_mfma_f32_16x16x32_f16(fah[i], fbl[j], acc[i][j], 0, 0, 0);
                acc[i][j] = __builtin_amdgcn_mfma_f32_16x16x32_f16(fal[i], fbh[j], acc[i][j], 0, 0, 0);
            }
    }

    const bool isP = (rowBase < 512);   // uniform per block (by<4)
    #pragma unroll
    for (int i = 0; i < 4; ++i) {
        const int rg0 = rowBase + wr * 64 + i * 16 + (l >> 4) * 4;
        #pragma unroll
        for (int j = 0; j < 4; ++j) {
            const int cg = colBase + wc * 64 + j * 16 + frow;
            #pragma unroll
            for (int r = 0; r < 4; ++r) {
                int row = rg0 + r;
                float v = acc[i][j][r] + rowbias[row];
                if (isP) {
                    Pkt[(size_t)row * 16384 + cg] = v;
                } else {
                    int vr = row - 512;
                    _Float16 hh = (_Float16)v;
                    VtH[(size_t)vr * 16384 + cg] = hh;
                    VtL[(size_t)vr * 16384 + cg] = (_Float16)(v - (float)hh);
                }
            }
        }
    }
}

// ---------------------------------------------------------------------------
// WcatH/L[z*512+col][time] = split( sum_dd Wrf[h][dd][r] * WtT[z][h*64+dd][time] )
// ---------------------------------------------------------------------------
__global__ __launch_bounds__(256) void projw_T(const float* __restrict__ WtT3,
        const float* __restrict__ Wrf,
        _Float16* __restrict__ WcH, _Float16* __restrict__ WcL) {
    int z = blockIdx.y;
    int col = blockIdx.x;
    int h = col >> 5, r = col & 31;
    __shared__ float wsh[64];
    int t = threadIdx.x;
    if (t < 64) wsh[t] = Wrf[(size_t)(h * 64 + t) * 32 + r];
    __syncthreads();
    const float* base = WtT3 + (size_t)z * 1048576 + (size_t)(h * 64) * 1024;
    float acc0 = 0.f, acc1 = 0.f, acc2 = 0.f, acc3 = 0.f;
    for (int dd = 0; dd < 64; ++dd) {
        float wv = wsh[dd];
        const float* row = base + (size_t)dd * 1024;
        acc0 = fmaf(wv, row[t], acc0);
        acc1 = fmaf(wv, row[t + 256], acc1);
        acc2 = fmaf(wv, row[t + 512], acc2);
        acc3 = fmaf(wv, row[t + 768], acc3);
    }
    size_t o = (size_t)(z * 512 + col) * 1024;
    float vals[4] = {acc0, acc1, acc2, acc3};
    #pragma unroll
    for (int q = 0; q < 4; ++q) {
        int f = t + q * 256;
        _Float16 hh = (_Float16)vals[q];
        WcH[o + f] = hh;
        WcL[o + f] = (_Float16)(vals[q] - (float)hh);
    }
}

// ---------------------------------------------------------------------------
// phi_q: Pq[m][512] f32 -> phi_q hi/lo [m][1024]: col h*64+cc = cos, +32 = sin
// ---------------------------------------------------------------------------
__global__ __launch_bounds__(256) void phi_q(const float* __restrict__ Pq,
        _Float16* __restrict__ qh, _Float16* __restrict__ ql) {
    int idx = blockIdx.x * 256 + threadIdx.x;   // 16384*128
    int m = idx >> 7, v4 = idx & 127;
    float4 p = ((const float4*)(Pq + (size_t)m * 512))[v4];
    int h = v4 >> 3, cc = (v4 & 7) * 4;
    float c[4], s[4];
    sincosf(p.x, &s[0], &c[0]);
    sincosf(p.y, &s[1], &c[1]);
    sincosf(p.z, &s[2], &c[2]);
    sincosf(p.w, &s[3], &c[3]);
    half4v chv, clv, shv, slv;
    #pragma unroll
    for (int q = 0; q < 4; ++q) {
        float cv = c[q] * INV_SQRT_RH, sv = s[q] * INV_SQRT_RH;
        _Float16 chh = (_Float16)cv, shh = (_Float16)sv;
        chv[q] = chh; clv[q] = (_Float16)(cv - (float)chh);
        shv[q] = shh; slv[q] = (_Float16)(sv - (float)shh);
    }
    size_t o = (size_t)m * 1024 + h * 64 + cc;
    *(half4v*)(qh + o) = chv;
    *(half4v*)(qh + o + 32) = shv;
    *(half4v*)(ql + o) = clv;
    *(half4v*)(ql + o + 32) = slv;
}

// ---------------------------------------------------------------------------
// kv_mfma: KVt[bh][dd][r] += sum_{m in batch b} Vt[h*64+dd][m] * phi_k[r][m];
// Ksum folded.  *** m-base = b*4096 + ch*256 (batch-local chunks!) ***
// grid (16 chunks, 64 bh); 8 iters x 32 m; phi_k on the fly -> swizzled LDS.
// ---------------------------------------------------------------------------
__global__ __launch_bounds__(256) void kv_mfma(
    const _Float16* __restrict__ VtH, const _Float16* __restrict__ VtL,
    const float* __restrict__ Pkt, float* __restrict__ KVt, float* __restrict__ Ksum)
{
    int ch = blockIdx.x, bh = blockIdx.y;
    int b = bh >> 4, h = bh & 15;
    const int mbase = b * 4096 + ch * 256;   // batch-local m-chunk
    __shared__ _Float16 lds[8192];   // AH 0, AL 2048, BH 4096, BL 6144 (halves)
    const int t = threadIdx.x, w = t >> 6, l = t & 63;

    // A staging: thread t -> (row t>>2, chunk t&3), swizzled source
    const int arow = t >> 2;
    const int acb = (t & 3) ^ ((arow >> 1) & 3);
    const size_t abase = (size_t)(h * 64 + arow) * 16384 + mbase + acb * 8;
    _Float16* dAh = lds + t * 8;
    _Float16* dAl = lds + 2048 + t * 8;

    // B (phi_k) staging: thread t -> P-row prow=t>>3, m-quad mq=t&7
    const int prow = t >> 3, mq = t & 7;
    const float* pP = Pkt + (size_t)(h * 32 + prow) * 16384 + mbase + mq * 4;
    const int pcb = (mq >> 1) ^ ((prow >> 1) & 3);
    const int inner = (mq & 1) * 4;
    const int coff = 4096 + prow * 32 + pcb * 8 + inner;          // cos row = prow
    const int soff = 4096 + (prow + 32) * 32 + pcb * 8 + inner;   // sin row = prow+32

    // fragment offsets
    const int frow = l & 15, kb = l >> 4;
    const int ar = w * 16 + frow;
    const int aoff = ar * 32 + ((kb ^ ((ar >> 1) & 3)) << 3);
    int boff[4];
    #pragma unroll
    for (int j = 0; j < 4; ++j) {
        int br = j * 16 + frow;
        boff[j] = 4096 + br * 32 + ((kb ^ ((br >> 1) & 3)) << 3);
    }

    f32x4 acc[4];
    #pragma unroll
    for (int j = 0; j < 4; ++j) acc[j] = (f32x4){0.0f, 0.0f, 0.0f, 0.0f};
    float ksc = 0.0f, kss = 0.0f;

    for (int it = 0; it < 8; ++it) {
        __syncthreads();
        GLD16(VtH + abase + it * 32, dAh);
        GLD16(VtL + abase + it * 32, dAl);
        float4 pv = *(const float4*)(pP + it * 32);
        float c[4], s[4];
        sincosf(pv.x, &s[0], &c[0]);
        sincosf(pv.y, &s[1], &c[1]);
        sincosf(pv.z, &s[2], &c[2]);
        sincosf(pv.w, &s[3], &c[3]);
        half4v chv, clv, shv, slv;
        #pragma unroll
        for (int q = 0; q < 4; ++q) {
            float cv = c[q] * INV_SQRT_RH, sv = s[q] * INV_SQRT_RH;
            ksc += cv; kss += sv;
            _Float16 chh = (_Float16)cv, shh = (_Float16)sv;
            chv[q] = chh; clv[q] = (_Float16)(cv - (float)chh);
            shv[q] = shh; slv[q] = (_Float16)(sv - (float)shh);
        }
        *(half4v*)(lds + coff) = chv;
        *(half4v*)(lds + 2048 + coff) = clv;
        *(half4v*)(lds + soff) = shv;
        *(half4v*)(lds + 2048 + soff) = slv;
        __syncthreads();
        half8 fah = *(const half8*)&lds[aoff];
        half8 fal = *(const half8*)&lds[2048 + aoff];
        #pragma unroll
        for (int j = 0; j < 4; ++j) {
            half8 fbh = *(const half8*)&lds[boff[j]];
            half8 fbl = *(const half8*)&lds[2048 + boff[j]];
            acc[j] = __builtin_amdgcn_mfma_f32_16x16x32_f16(fah, fbh, acc[j], 0, 0, 0);
            acc[j] = __builtin_amdgcn_mfma_f32_16x16x32_f16(fah, fbl, acc[j], 0, 0, 0);
            acc[j] = __builtin_amdgcn_mfma_f32_16x16x32_f16(fal, fbh, acc[j], 0, 0, 0);
        }
    }

    // Ksum: reduce over the 8 m-quad lanes of each P-row, then atomic
    #pragma unroll
    for (int off = 1; off < 8; off <<= 1) {
        ksc += __shfl_xor(ksc, off);
        kss += __shfl_xor(kss, off);
    }
    if (mq == 0) {
        atomicAdd(&Ksum[bh * 64 + prow], ksc);
        atomicAdd(&Ksum[bh * 64 + 32 + prow], kss);
    }

    // KVt atomics: dd = w*16 + (l>>4)*4 + r ; rcol = j*16 + frow
    #pragma unroll
    for (int j = 0; j < 4; ++j)
        #pragma unroll
        for (int r = 0; r < 4; ++r)
            atomicAdd(&KVt[(size_t)bh * 4096 + (w * 16 + (l >> 4) * 4 + r) * 64 + j * 16 + frow],
                      acc[j][r]);
}

// ---------------------------------------------------------------------------
// battn: per bh build B = [80][64] hi/lo: rows 0-63 KVt[dd][r], row 64 Ksum, rest 0
// ---------------------------------------------------------------------------
__global__ __launch_bounds__(256) void battn_build(const float* __restrict__ KVt,
        const float* __restrict__ Ksum,
        _Float16* __restrict__ BaH, _Float16* __restrict__ BaL) {
    int bh = blockIdx.x, t = threadIdx.x;
    for (int idx = t; idx < 5120; idx += 256) {
        int row = idx >> 6, k = idx & 63;
        float v = 0.0f;
        if (row < 64) v = KVt[(size_t)bh * 4096 + row * 64 + k];
        else if (row == 64) v = Ksum[bh * 64 + k];
        _Float16 hh = (_Float16)v;
        BaH[(size_t)bh * 5120 + idx] = hh;
        BaL[(size_t)bh * 5120 + idx] = (_Float16)(v - (float)hh);
    }
}

// ---------------------------------------------------------------------------
// attn_mfma: per (m-tile 128, bh): C[m][0..79] = phi_q[m][:] @ Battn^T;
// col<64 = num, col 64 = den; write attn = num/(den+1e-6) as fp16 hi/lo.
// ---------------------------------------------------------------------------
__global__ __launch_bounds__(256) void attn_mfma(
    const _Float16* __restrict__ qh, const _Float16* __restrict__ ql,
    const _Float16* __restrict__ BaH, const _Float16* __restrict__ BaL,
    _Float16* __restrict__ attnH, _Float16* __restrict__ attnL)
{
    int bh = blockIdx.y, b = bh >> 4, h = bh & 15;
    int m0 = b * 4096 + blockIdx.x * 128;
    __shared__ _Float16 lds[16384];   // AH [128][64] @0, AL @8192
    const int t = threadIdx.x, w = t >> 6, l = t & 63;

    #pragma unroll
    for (int sub = 0; sub < 4; ++sub) {
        int slot = sub * 256 + t;
        int row = slot >> 3, cl = slot & 7, sc = cl ^ (row & 7);
        size_t src = (size_t)(m0 + row) * 1024 + h * 64 + sc * 8;
        GLD16(qh + src, lds + slot * 8);
        GLD16(ql + src, lds + 8192 + slot * 8);
    }
    __syncthreads();

    const int frow = l & 15, kb = l >> 4;
    f32x4 acc[2][5];
    #pragma unroll
    for (int mt = 0; mt < 2; ++mt)
        #pragma unroll
        for (int j = 0; j < 5; ++j)
            acc[mt][j] = (f32x4){0.0f, 0.0f, 0.0f, 0.0f};

    #pragma unroll
    for (int kk = 0; kk < 2; ++kk) {
        half8 fa[2], fb_lo_a[2];
        #pragma unroll
        for (int mt = 0; mt < 2; ++mt) {
            int ar = w * 32 + mt * 16 + frow;
            int c = kk * 4 + kb;
            int off = ar * 64 + ((c ^ (ar & 7)) << 3);
            fa[mt] = *(const half8*)&lds[off];
            fb_lo_a[mt] = *(const half8*)&lds[8192 + off];
        }
        #pragma unroll
        for (int j = 0; j < 5; ++j) {
            size_t bo = (size_t)bh * 5120 + (j * 16 + frow) * 64 + kk * 32 + kb * 8;
            half8 fbh = *(const half8*)(BaH + bo);
            half8 fbl = *(const half8*)(BaL + bo);
            #pragma unroll
            for (int mt = 0; mt < 2; ++mt) {
                acc[mt][j] = __builtin_amdgcn_mfma_f32_16x16x32_f16(fa[mt], fbh, acc[mt][j], 0, 0, 0);
                acc[mt][j] = __builtin_amdgcn_mfma_f32_16x16x32_f16(fa[mt], fbl, acc[mt][j], 0, 0, 0);
                acc[mt][j] = __builtin_amdgcn_mfma_f32_16x16x32_f16(fb_lo_a[mt], fbh, acc[mt][j], 0, 0, 0);
            }
        }
    }

    #pragma unroll
    for (int mt = 0; mt < 2; ++mt) {
        float dn[4];
        #pragma unroll
        for (int r = 0; r < 4; ++r)
            dn[r] = __shfl(acc[mt][4][r], l & 48);   // den lives at (l&15)==0
        #pragma unroll
        for (int j = 0; j < 4; ++j) {
            #pragma unroll
            for (int r = 0; r < 4; ++r) {
                float v = acc[mt][j][r] / (dn[r] + 1e-6f);
                _Float16 hh = (_Float16)v;
                size_t o = (size_t)(m0 + w * 32 + mt * 16 + (l >> 4) * 4 + r) * 1024
                         + h * 64 + j * 16 + frow;
                attnH[o] = hh;
                attnL[o] = (_Float16)(v - (float)hh);
            }
        }
    }
}

extern "C" void kernel_launch(void* const* d_in, const int* in_sizes, int n_in,
                              void* d_out, int out_size, void* d_ws, size_t ws_size,
                              hipStream_t stream) {
    const float* x   = (const float*)d_in[0];
    const float* Wq  = (const float*)d_in[1];
    const float* bq  = (const float*)d_in[2];
    const float* Wk  = (const float*)d_in[3];
    const float* bk  = (const float*)d_in[4];
    const float* Wv  = (const float*)d_in[5];
    const float* bv  = (const float*)d_in[6];
    const float* Wp  = (const float*)d_in[7];
    const float* bp  = (const float*)d_in[8];
    const float* Wrf = (const float*)d_in[9];
    const float* brf = (const float*)d_in[10];
    float* out = (float*)d_out;
    float* ws  = (float*)d_ws;

    const size_t M1 = 1048576;
    // ---- f32 zone ----
    float* C_      = ws;                       // preproc only
    float* Gt      = ws + 1 * M1;              // preproc only
    float* WtT3    = ws + 2 * M1;              // preproc only
    float* WpGT_f  = ws + 5 * M1;              // preproc only
    float* Pq      = ws;                       // after preproc (aliases C_..)
    float* Pkt     = ws + 8 * M1;              // 8..16M
    float* bias_cat= ws + 16 * M1;             // 2048
    float* bG      = ws + 16 * M1 + 2048;      // 1024
    float* KVt     = ws + 16 * M1 + 8192;      // 262144
    float* Ksum    = KVt + 262144;             // 4096

    // ---- halves zone ----
    _Float16* wsH  = (_Float16*)(ws + 17 * M1);
    _Float16* Ch   = wsH;
    _Float16* Cl   = wsH + 1 * M1;
    _Float16* Gth  = wsH + 2 * M1;
    _Float16* Gtl  = wsH + 3 * M1;
    _Float16* WpTh = wsH + 4 * M1;
    _Float16* WpTl = wsH + 5 * M1;
    _Float16* W3h  = wsH + 6 * M1;
    _Float16* W3l  = wsH + 9 * M1;
    _Float16* BaH  = wsH;                      // battn (alias dead preproc zone)
    _Float16* BaL  = wsH + 1 * M1;
    _Float16* xh   = wsH + 12 * M1;
    _Float16* xl   = wsH + 28 * M1;
    _Float16* phiqH= xh;                       // alias: x dead after GEMM1b
    _Float16* phiqL= xl;
    _Float16* WcatH= wsH + 44 * M1;
    _Float16* WcatL= wsH + 46 * M1;
    _Float16* WpGTh= wsH + 48 * M1;
    _Float16* WpGTl= wsH + 49 * M1;
    _Float16* VtH  = wsH + 50 * M1;
    _Float16* VtL  = wsH + 66 * M1;
    _Float16* attnH= VtH;                      // alias: Vt dead after kv_mfma
    _Float16* attnL= VtL;

    // --- DFT matrices + splits ---
    build_CG<<<8192, 256, 0, stream>>>(C_, Gt);
    split_plain<<<4096, 256, 0, stream>>>(x, xh, xl, 4194304);
    split_plain<<<1024, 256, 0, stream>>>(C_, Ch, Cl, 262144);
    split_plain<<<1024, 256, 0, stream>>>(Gt, Gth, Gtl, 262144);
    split_T<<<dim3(32, 32), 256, 0, stream>>>(Wp, 1024, WpTh, WpTl);
    split_plain<<<1024, 256, 0, stream>>>(Wq, W3h, W3l, 262144);
    split_plain<<<1024, 256, 0, stream>>>(Wk, W3h + 1048576, W3l + 1048576, 262144);
    split_plain<<<1024, 256, 0, stream>>>(Wv, W3h + 2097152, W3l + 2097152, 262144);

    // --- preprocessing GEMMs (matrix cores) ---
    gemm_hilo3<<<dim3(8, 8, 3), 256, 0, stream>>>(W3h, W3l, Ch, Cl, WtT3);
    gemm_hilo<false><<<dim3(8, 8), 256, 0, stream>>>(Gth, Gtl, WpTh, WpTl, nullptr, WpGT_f, 1024, 1024);
    split_plain<<<1024, 256, 0, stream>>>(WpGT_f, WpGTh, WpGTl, 262144);
    projw_T<<<dim3(512, 2), 256, 0, stream>>>(WtT3, Wrf, WcatH, WcatL);
    split_plain<<<1024, 256, 0, stream>>>(WtT3 + 2 * M1, WcatH + 1048576, WcatL + 1048576, 262144);
    build_bproj<<<2, 256, 0, stream>>>(bq, Wrf, brf, bias_cat);
    build_bproj<<<2, 256, 0, stream>>>(bk, Wrf, brf, bias_cat + 512);
    copy_vec<<<4, 256, 0, stream>>>(bv, bias_cat + 1024, 1024);
    build_bG<<<1024, 256, 0, stream>>>(bp, Gt, bG);

    // --- GEMM1a: Pq = x @ WcatQ^T + bq'  ([16384][512] f32) ---
    gemm_hilo<true><<<dim3(4, 128), 256, 0, stream>>>(xh, xl, WcatH, WcatL, bias_cat, Pq, 512, 1024);

    // --- GEMM1b: [Pkt | Vt] = Wcat[512..] @ x^T + rowbias (transposed outputs) ---
    gemm_pkvt<<<dim3(128, 12), 256, 0, stream>>>(WcatH + (size_t)512 * 1024, WcatL + (size_t)512 * 1024,
                                                 xh, xl, bias_cat + 512, Pkt, VtH, VtL);

    // --- phi_q (x buffers now dead -> reused) ---
    phi_q<<<8192, 256, 0, stream>>>(Pq, phiqH, phiqL);

    // --- linear attention on matrix cores ---
    zero_kernel<<<(266240 + 255) / 256, 256, 0, stream>>>(KVt, 266240);
    kv_mfma<<<dim3(16, 64), 256, 0, stream>>>(VtH, VtL, Pkt, KVt, Ksum);
    battn_build<<<64, 256, 0, stream>>>(KVt, Ksum, BaH, BaL);
    attn_mfma<<<dim3(32, 64), 256, 0, stream>>>(phiqH, phiqL, BaH, BaL, attnH, attnL);

    // --- GEMM2: out = attn @ WpG + bG (irfft folded in) ---
    gemm_hilo<true><<<dim3(8, 128), 256, 0, stream>>>(attnH, attnL, WpGTh, WpGTl, bG, out, 1024, 1024);
}